// Round 1
// baseline (1210.462 us; speedup 1.0000x reference)
//
#include <hip/hip_runtime.h>
#include <hip/hip_bf16.h>

#define NFEAT 128
#define NODES_PER_BLOCK 16

// ---------------------------------------------------------------------------
// K1: fuse weights.  W1t[i][o] = sum_k lin[o][k] * Ws[k][i]  (k-major layout
// so the GEMM kernel reads coalesced).  Also b_total = lin@(Ws_b+Wn_b+Wu_b)+lin_b.
// grid = 128 (i), block = 128 (o)
// ---------------------------------------------------------------------------
__global__ void fuse_weights(const float* __restrict__ Ws, const float* __restrict__ Wn,
                             const float* __restrict__ Wu,
                             const float* __restrict__ Wsb, const float* __restrict__ Wnb,
                             const float* __restrict__ Wub,
                             const float* __restrict__ lin, const float* __restrict__ linb,
                             float* __restrict__ W1t, float* __restrict__ W2t,
                             float* __restrict__ W3t, float* __restrict__ btot) {
    __shared__ float cs[NFEAT], cn[NFEAT], cu[NFEAT], bsum[NFEAT];
    const int i = blockIdx.x;
    const int o = threadIdx.x;
    // column i of each W (indexed by k)
    cs[o] = Ws[o * NFEAT + i];
    cn[o] = Wn[o * NFEAT + i];
    cu[o] = Wu[o * NFEAT + i];
    bsum[o] = Wsb[o] + Wnb[o] + Wub[o];
    __syncthreads();
    float a1 = 0.f, a2 = 0.f, a3 = 0.f, ab = 0.f;
    #pragma unroll 4
    for (int k = 0; k < NFEAT; ++k) {
        const float l = lin[o * NFEAT + k];
        a1 += l * cs[k];
        a2 += l * cn[k];
        a3 += l * cu[k];
        ab += l * bsum[k];
    }
    W1t[i * NFEAT + o] = a1;
    W2t[i * NFEAT + o] = a2;
    W3t[i * NFEAT + o] = a3;
    if (i == 0) btot[o] = ab + linb[o];
}

// ---------------------------------------------------------------------------
// K2: edge aggregation with fp32 atomics.
// One 64-lane wave per edge; each lane handles 2 features (float2).
// ---------------------------------------------------------------------------
__global__ void edge_agg(const float* __restrict__ h, const float* __restrict__ e,
                         const int* __restrict__ src, const int* __restrict__ dst,
                         float* __restrict__ sum_p, float* __restrict__ sum_u,
                         float* __restrict__ deg, int n_edges) {
    const int tid  = blockIdx.x * blockDim.x + threadIdx.x;
    const int edge = tid >> 6;
    const int lane = tid & 63;
    if (edge >= n_edges) return;
    const int s = src[edge];
    const int d = dst[edge];
    const float ev = e[edge];
    const float2 hv = *(const float2*)(h + (size_t)s * NFEAT + lane * 2);
    float* up = sum_u + (size_t)d * NFEAT + lane * 2;
    float* pp = sum_p + (size_t)d * NFEAT + lane * 2;
    atomicAdd(up,     hv.x);
    atomicAdd(up + 1, hv.y);
    atomicAdd(pp,     ev * hv.x);
    atomicAdd(pp + 1, ev * hv.y);
    if (lane == 0) atomicAdd(deg + d, 1.0f);
}

// ---------------------------------------------------------------------------
// K3: fused triple-GEMM epilogue.
// out[n][o] = btot[o] + sum_k  h[n][k]*W1t[k][o]
//                     + (sum_p[n][k]/deg~)*W2t[k][o]
//                     + (sum_u[n][k]/deg~)*W3t[k][o]
// block = 128 threads (one output column each), 16 nodes per block.
// ---------------------------------------------------------------------------
__global__ void fused_gemm(const float* __restrict__ h, const float* __restrict__ sum_p,
                           const float* __restrict__ sum_u, const float* __restrict__ deg,
                           const float* __restrict__ W1t, const float* __restrict__ W2t,
                           const float* __restrict__ W3t, const float* __restrict__ btot,
                           float* __restrict__ out, int n_nodes) {
    __shared__ float sh[NODES_PER_BLOCK][NFEAT];
    __shared__ float sp[NODES_PER_BLOCK][NFEAT];
    __shared__ float su[NODES_PER_BLOCK][NFEAT];
    const int o  = threadIdx.x;
    const int n0 = blockIdx.x * NODES_PER_BLOCK;

    for (int idx = threadIdx.x; idx < NODES_PER_BLOCK * NFEAT; idx += NFEAT) {
        const int n = idx >> 7;
        const int k = idx & (NFEAT - 1);
        const int gn = n0 + n;
        if (gn < n_nodes) {
            const float inv = 1.0f / fmaxf(deg[gn], 1.0f);
            sh[n][k] = h[(size_t)gn * NFEAT + k];
            sp[n][k] = sum_p[(size_t)gn * NFEAT + k] * inv;
            su[n][k] = sum_u[(size_t)gn * NFEAT + k] * inv;
        } else {
            sh[n][k] = 0.f; sp[n][k] = 0.f; su[n][k] = 0.f;
        }
    }
    __syncthreads();

    const float bt = btot[o];
    float acc[NODES_PER_BLOCK];
    #pragma unroll
    for (int n = 0; n < NODES_PER_BLOCK; ++n) acc[n] = bt;

    for (int k = 0; k < NFEAT; ++k) {
        const float w1 = W1t[k * NFEAT + o];
        const float w2 = W2t[k * NFEAT + o];
        const float w3 = W3t[k * NFEAT + o];
        #pragma unroll
        for (int n = 0; n < NODES_PER_BLOCK; ++n)
            acc[n] += sh[n][k] * w1 + sp[n][k] * w2 + su[n][k] * w3;
    }

    #pragma unroll
    for (int n = 0; n < NODES_PER_BLOCK; ++n) {
        const int gn = n0 + n;
        if (gn < n_nodes) out[(size_t)gn * NFEAT + o] = acc[n];
    }
}

extern "C" void kernel_launch(void* const* d_in, const int* in_sizes, int n_in,
                              void* d_out, int out_size, void* d_ws, size_t ws_size,
                              hipStream_t stream) {
    const float* h    = (const float*)d_in[0];
    const float* e    = (const float*)d_in[1];
    const int*   src  = (const int*)d_in[2];
    const int*   dst  = (const int*)d_in[3];
    const float* Ws_w = (const float*)d_in[4];
    const float* Ws_b = (const float*)d_in[5];
    const float* Wn_w = (const float*)d_in[6];
    const float* Wn_b = (const float*)d_in[7];
    const float* Wu_w = (const float*)d_in[8];
    const float* Wu_b = (const float*)d_in[9];
    const float* lin_w = (const float*)d_in[10];
    const float* lin_b = (const float*)d_in[11];
    float* out = (float*)d_out;

    const int n_nodes = in_sizes[0] / NFEAT;
    const int n_edges = in_sizes[2];

    // workspace layout (floats)
    float* ws     = (float*)d_ws;
    float* sum_p  = ws;                                   // n_nodes*128
    float* sum_u  = sum_p + (size_t)n_nodes * NFEAT;      // n_nodes*128
    float* deg    = sum_u + (size_t)n_nodes * NFEAT;      // n_nodes
    float* W1t    = deg + n_nodes;                        // 128*128
    float* W2t    = W1t + NFEAT * NFEAT;
    float* W3t    = W2t + NFEAT * NFEAT;
    float* btot   = W3t + NFEAT * NFEAT;                  // 128

    // zero the accumulation buffers (sum_p, sum_u, deg are contiguous)
    const size_t zero_bytes = ((size_t)n_nodes * NFEAT * 2 + n_nodes) * sizeof(float);
    hipMemsetAsync(sum_p, 0, zero_bytes, stream);

    fuse_weights<<<NFEAT, NFEAT, 0, stream>>>(Ws_w, Wn_w, Wu_w, Ws_b, Wn_b, Wu_b,
                                              lin_w, lin_b, W1t, W2t, W3t, btot);

    const int threads_total = n_edges * 64;
    edge_agg<<<(threads_total + 255) / 256, 256, 0, stream>>>(
        h, e, src, dst, sum_p, sum_u, deg, n_edges);

    const int n_blocks = (n_nodes + NODES_PER_BLOCK - 1) / NODES_PER_BLOCK;
    fused_gemm<<<n_blocks, NFEAT, 0, stream>>>(h, sum_p, sum_u, deg,
                                               W1t, W2t, W3t, btot, out, n_nodes);
}

// Round 2
// 295.443 us; speedup vs baseline: 4.0971x; 4.0971x over previous
//
#include <hip/hip_runtime.h>
#include <hip/hip_bf16.h>

#define NFEAT 128
#define NODES_PER_BLOCK 16

// ---------------------------------------------------------------------------
// K1: fuse weights.  W1t[k][o] = sum_j lin[o][j] * Ws[j][k]  (k-major so the
// GEMM kernel reads coalesced).  btot = lin@(Ws_b+Wn_b+Wu_b) + lin_b.
// grid = 128 (k), block = 128 (o)
// ---------------------------------------------------------------------------
__global__ void fuse_weights(const float* __restrict__ Ws, const float* __restrict__ Wn,
                             const float* __restrict__ Wu,
                             const float* __restrict__ Wsb, const float* __restrict__ Wnb,
                             const float* __restrict__ Wub,
                             const float* __restrict__ lin, const float* __restrict__ linb,
                             float* __restrict__ W1t, float* __restrict__ W2t,
                             float* __restrict__ W3t, float* __restrict__ btot) {
    __shared__ float cs[NFEAT], cn[NFEAT], cu[NFEAT], bsum[NFEAT];
    const int i = blockIdx.x;
    const int o = threadIdx.x;
    cs[o] = Ws[o * NFEAT + i];
    cn[o] = Wn[o * NFEAT + i];
    cu[o] = Wu[o * NFEAT + i];
    bsum[o] = Wsb[o] + Wnb[o] + Wub[o];
    __syncthreads();
    float a1 = 0.f, a2 = 0.f, a3 = 0.f, ab = 0.f;
    #pragma unroll 4
    for (int k = 0; k < NFEAT; ++k) {
        const float l = lin[o * NFEAT + k];
        a1 += l * cs[k];
        a2 += l * cn[k];
        a3 += l * cu[k];
        ab += l * bsum[k];
    }
    W1t[i * NFEAT + o] = a1;
    W2t[i * NFEAT + o] = a2;
    W3t[i * NFEAT + o] = a3;
    if (i == 0) btot[o] = ab + linb[o];
}

// ---------------------------------------------------------------------------
// K2: degree count (int atomics, cheap)
// ---------------------------------------------------------------------------
__global__ void count_deg(const int* __restrict__ dst, int* __restrict__ cnt,
                          int n_edges) {
    const int i = blockIdx.x * blockDim.x + threadIdx.x;
    if (i < n_edges) atomicAdd(&cnt[dst[i]], 1);
}

// ---------------------------------------------------------------------------
// K3: single-block exclusive prefix scan of cnt -> offsets (+cursor copy).
// block = 1024, each thread handles ceil(n/1024) elements.
// ---------------------------------------------------------------------------
__global__ void scan_offsets(const int* __restrict__ cnt, int* __restrict__ offsets,
                             int* __restrict__ cursor, int n_nodes, int n_edges) {
    __shared__ int part[1024];
    const int t = threadIdx.x;
    const int chunk = (n_nodes + 1023) / 1024;
    const int b = t * chunk;
    int s = 0;
    for (int i = 0; i < chunk; ++i) {
        const int idx = b + i;
        if (idx < n_nodes) s += cnt[idx];
    }
    part[t] = s;
    __syncthreads();
    // Hillis-Steele inclusive scan over 1024 partials
    for (int d = 1; d < 1024; d <<= 1) {
        const int v = (t >= d) ? part[t - d] : 0;
        __syncthreads();
        part[t] += v;
        __syncthreads();
    }
    int run = part[t] - s;  // exclusive base for this thread's chunk
    for (int i = 0; i < chunk; ++i) {
        const int idx = b + i;
        if (idx < n_nodes) {
            offsets[idx] = run;
            cursor[idx]  = run;
            run += cnt[idx];
        }
    }
    if (t == 0) offsets[n_nodes] = n_edges;
}

// ---------------------------------------------------------------------------
// K4: scatter edges into CSR slots: eidx[pos] = {src, bits(e)}
// ---------------------------------------------------------------------------
__global__ void scatter_edges(const int* __restrict__ src, const int* __restrict__ dst,
                              const float* __restrict__ e, int* __restrict__ cursor,
                              int2* __restrict__ eidx, int n_edges) {
    const int i = blockIdx.x * blockDim.x + threadIdx.x;
    if (i >= n_edges) return;
    const int d = dst[i];
    const int pos = atomicAdd(&cursor[d], 1);
    eidx[pos] = make_int2(src[i], __float_as_int(e[i]));
}

// ---------------------------------------------------------------------------
// K5: per-node gather-reduce. One 64-lane wave per node, 2 feats/lane.
// Writes MEAN values directly (u-mean and (u*e)-mean).
// ---------------------------------------------------------------------------
__global__ void aggregate(const float* __restrict__ h, const int2* __restrict__ eidx,
                          const int* __restrict__ offsets,
                          float* __restrict__ mean_p, float* mean_u, int n_nodes) {
    const int wave = (int)((blockIdx.x * blockDim.x + threadIdx.x) >> 6);
    const int lane = threadIdx.x & 63;
    if (wave >= n_nodes) return;
    const int node = wave;
    const int beg = offsets[node], end = offsets[node + 1];
    float2 su = make_float2(0.f, 0.f), sp = make_float2(0.f, 0.f);
    const float* hp = h + lane * 2;
    int j = beg;
    for (; j + 2 <= end; j += 2) {
        const int2 e0 = eidx[j], e1 = eidx[j + 1];
        const float2 h0 = *(const float2*)(hp + (size_t)e0.x * NFEAT);
        const float2 h1 = *(const float2*)(hp + (size_t)e1.x * NFEAT);
        const float ev0 = __int_as_float(e0.y), ev1 = __int_as_float(e1.y);
        su.x += h0.x + h1.x;
        su.y += h0.y + h1.y;
        sp.x += ev0 * h0.x + ev1 * h1.x;
        sp.y += ev0 * h0.y + ev1 * h1.y;
    }
    if (j < end) {
        const int2 e0 = eidx[j];
        const float2 h0 = *(const float2*)(hp + (size_t)e0.x * NFEAT);
        const float ev0 = __int_as_float(e0.y);
        su.x += h0.x; su.y += h0.y;
        sp.x += ev0 * h0.x; sp.y += ev0 * h0.y;
    }
    const float inv = 1.0f / fmaxf((float)(end - beg), 1.0f);
    *(float2*)(mean_u + (size_t)node * NFEAT + lane * 2) =
        make_float2(su.x * inv, su.y * inv);
    *(float2*)(mean_p + (size_t)node * NFEAT + lane * 2) =
        make_float2(sp.x * inv, sp.y * inv);
}

// ---------------------------------------------------------------------------
// K6: fused triple-GEMM epilogue.
// out[n][o] = btot[o] + sum_k h[n][k]*W1t[k][o] + mp[n][k]*W2t[k][o]
//                     + mu[n][k]*W3t[k][o]
// NOTE: mean_u may alias out (d_out reused as scratch): each block stages its
// rows into LDS before writing those same rows, so no cross-block hazard.
// ---------------------------------------------------------------------------
__global__ void fused_gemm(const float* __restrict__ h, const float* __restrict__ mean_p,
                           const float* mean_u,
                           const float* __restrict__ W1t, const float* __restrict__ W2t,
                           const float* __restrict__ W3t, const float* __restrict__ btot,
                           float* out, int n_nodes) {
    __shared__ float sh[NODES_PER_BLOCK][NFEAT];
    __shared__ float sp[NODES_PER_BLOCK][NFEAT];
    __shared__ float su[NODES_PER_BLOCK][NFEAT];
    const int o  = threadIdx.x;
    const int n0 = blockIdx.x * NODES_PER_BLOCK;

    for (int idx = threadIdx.x; idx < NODES_PER_BLOCK * NFEAT; idx += NFEAT) {
        const int n = idx >> 7;
        const int k = idx & (NFEAT - 1);
        const int gn = n0 + n;
        if (gn < n_nodes) {
            sh[n][k] = h[(size_t)gn * NFEAT + k];
            sp[n][k] = mean_p[(size_t)gn * NFEAT + k];
            su[n][k] = mean_u[(size_t)gn * NFEAT + k];
        } else {
            sh[n][k] = 0.f; sp[n][k] = 0.f; su[n][k] = 0.f;
        }
    }
    __syncthreads();

    const float bt = btot[o];
    float acc[NODES_PER_BLOCK];
    #pragma unroll
    for (int n = 0; n < NODES_PER_BLOCK; ++n) acc[n] = bt;

    for (int k = 0; k < NFEAT; ++k) {
        const float w1 = W1t[k * NFEAT + o];
        const float w2 = W2t[k * NFEAT + o];
        const float w3 = W3t[k * NFEAT + o];
        #pragma unroll
        for (int n = 0; n < NODES_PER_BLOCK; ++n)
            acc[n] += sh[n][k] * w1 + sp[n][k] * w2 + su[n][k] * w3;
    }

    #pragma unroll
    for (int n = 0; n < NODES_PER_BLOCK; ++n) {
        const int gn = n0 + n;
        if (gn < n_nodes) out[(size_t)gn * NFEAT + o] = acc[n];
    }
}

extern "C" void kernel_launch(void* const* d_in, const int* in_sizes, int n_in,
                              void* d_out, int out_size, void* d_ws, size_t ws_size,
                              hipStream_t stream) {
    const float* h     = (const float*)d_in[0];
    const float* e     = (const float*)d_in[1];
    const int*   src   = (const int*)d_in[2];
    const int*   dst   = (const int*)d_in[3];
    const float* Ws_w  = (const float*)d_in[4];
    const float* Ws_b  = (const float*)d_in[5];
    const float* Wn_w  = (const float*)d_in[6];
    const float* Wn_b  = (const float*)d_in[7];
    const float* Wu_w  = (const float*)d_in[8];
    const float* Wu_b  = (const float*)d_in[9];
    const float* lin_w = (const float*)d_in[10];
    const float* lin_b = (const float*)d_in[11];
    float* out = (float*)d_out;

    const int n_nodes = in_sizes[0] / NFEAT;
    const int n_edges = in_sizes[2];

    // ---- workspace layout ----
    char* ws = (char*)d_ws;
    float* mean_p = (float*)ws;                 ws += (size_t)n_nodes * NFEAT * 4;
    float* W1t    = (float*)ws;                 ws += NFEAT * NFEAT * 4;
    float* W2t    = (float*)ws;                 ws += NFEAT * NFEAT * 4;
    float* W3t    = (float*)ws;                 ws += NFEAT * NFEAT * 4;
    float* btot   = (float*)ws;                 ws += NFEAT * 4;
    int2*  eidx   = (int2*)ws;                  ws += (size_t)n_edges * 8;   // 8-aligned
    int*   cnt    = (int*)ws;                   ws += n_nodes * 4;
    int*   offs   = (int*)ws;                   ws += (n_nodes + 1) * 4;
    int*   cursor = (int*)ws;                   ws += n_nodes * 4;
    float* mean_u = out;  // reuse d_out as scratch for mean_u (see fused_gemm note)

    hipMemsetAsync(cnt, 0, (size_t)n_nodes * 4, stream);

    fuse_weights<<<NFEAT, NFEAT, 0, stream>>>(Ws_w, Wn_w, Wu_w, Ws_b, Wn_b, Wu_b,
                                              lin_w, lin_b, W1t, W2t, W3t, btot);

    count_deg<<<(n_edges + 255) / 256, 256, 0, stream>>>(dst, cnt, n_edges);

    scan_offsets<<<1, 1024, 0, stream>>>(cnt, offs, cursor, n_nodes, n_edges);

    scatter_edges<<<(n_edges + 255) / 256, 256, 0, stream>>>(src, dst, e, cursor,
                                                             eidx, n_edges);

    const int agg_blocks = (n_nodes * 64 + 255) / 256;
    aggregate<<<agg_blocks, 256, 0, stream>>>(h, eidx, offs, mean_p, mean_u, n_nodes);

    const int n_blocks = (n_nodes + NODES_PER_BLOCK - 1) / NODES_PER_BLOCK;
    fused_gemm<<<n_blocks, NFEAT, 0, stream>>>(h, mean_p, mean_u,
                                               W1t, W2t, W3t, btot, out, n_nodes);
}

// Round 3
// 248.284 us; speedup vs baseline: 4.8753x; 1.1899x over previous
//
#include <hip/hip_runtime.h>
#include <hip/hip_bf16.h>

#define NFEAT 128
#define NPB 16  // nodes per block in fused_gemm

// ---------------------------------------------------------------------------
// K1 "prep": blocks [0,128) fuse weights into Wcat[384][128] (k-major) and
// btot; blocks [128,..) count degrees with int atomics.
// Wcat rows: 0..127 = lin@Ws (k-major), 128..255 = lin@Wn, 256..383 = lin@Wu.
// ---------------------------------------------------------------------------
__global__ void prep(const float* __restrict__ Ws, const float* __restrict__ Wn,
                     const float* __restrict__ Wu,
                     const float* __restrict__ Wsb, const float* __restrict__ Wnb,
                     const float* __restrict__ Wub,
                     const float* __restrict__ lin, const float* __restrict__ linb,
                     const int* __restrict__ dst, int* __restrict__ cnt, int n_edges,
                     float* __restrict__ Wcat, float* __restrict__ btot) {
    if (blockIdx.x < NFEAT) {
        __shared__ float cs[NFEAT], cn[NFEAT], cu[NFEAT], bsum[NFEAT];
        const int i = blockIdx.x;   // k index
        const int o = threadIdx.x;  // only o<128 active
        if (o < NFEAT) {
            cs[o] = Ws[o * NFEAT + i];
            cn[o] = Wn[o * NFEAT + i];
            cu[o] = Wu[o * NFEAT + i];
            bsum[o] = Wsb[o] + Wnb[o] + Wub[o];
        }
        __syncthreads();
        if (o < NFEAT) {
            float a1 = 0.f, a2 = 0.f, a3 = 0.f, ab = 0.f;
            #pragma unroll 4
            for (int k = 0; k < NFEAT; ++k) {
                const float l = lin[o * NFEAT + k];
                a1 += l * cs[k];
                a2 += l * cn[k];
                a3 += l * cu[k];
                ab += l * bsum[k];
            }
            Wcat[(0 * NFEAT + i) * NFEAT + o] = a1;
            Wcat[(1 * NFEAT + i) * NFEAT + o] = a2;
            Wcat[(2 * NFEAT + i) * NFEAT + o] = a3;
            if (i == 0) btot[o] = ab + linb[o];
        }
    } else {
        const int i = (blockIdx.x - NFEAT) * 256 + threadIdx.x;
        if (i < n_edges) atomicAdd(&cnt[dst[i]], 1);
    }
}

// ---------------------------------------------------------------------------
// K2: exclusive prefix scan (single block of 1024 = 16 waves, shfl-based).
// ---------------------------------------------------------------------------
__global__ void scan_offsets(const int* __restrict__ cnt, int* __restrict__ offsets,
                             int* __restrict__ cursor, int n_nodes, int n_edges) {
    __shared__ int wbase_s[16];
    const int t = threadIdx.x;
    const int wave = t >> 6, lane = t & 63;
    const int chunk = (n_nodes + 1023) >> 10;
    const int b = t * chunk;
    int s = 0;
    for (int i = 0; i < chunk; ++i) {
        const int idx = b + i;
        if (idx < n_nodes) s += cnt[idx];
    }
    // wave-level inclusive scan
    int incl = s;
    #pragma unroll
    for (int d = 1; d < 64; d <<= 1) {
        const int v = __shfl_up(incl, d);
        if (lane >= d) incl += v;
    }
    __shared__ int wsum[16];
    if (lane == 63) wsum[wave] = incl;
    __syncthreads();
    if (t == 0) {
        int run = 0;
        for (int w = 0; w < 16; ++w) { wbase_s[w] = run; run += wsum[w]; }
    }
    __syncthreads();
    int run = wbase_s[wave] + (incl - s);  // exclusive prefix for this thread
    for (int i = 0; i < chunk; ++i) {
        const int idx = b + i;
        if (idx < n_nodes) {
            offsets[idx] = run;
            cursor[idx]  = run;
            run += cnt[idx];
        }
    }
    if (t == 0) offsets[n_nodes] = n_edges;
}

// ---------------------------------------------------------------------------
// K3: scatter edges into CSR slots: eidx[pos] = {src, bits(e)}
// ---------------------------------------------------------------------------
__global__ void scatter_edges(const int* __restrict__ src, const int* __restrict__ dst,
                              const float* __restrict__ e, int* __restrict__ cursor,
                              int2* __restrict__ eidx, int n_edges) {
    const int i = blockIdx.x * blockDim.x + threadIdx.x;
    if (i >= n_edges) return;
    const int d = dst[i];
    const int pos = atomicAdd(&cursor[d], 1);
    eidx[pos] = make_int2(src[i], __float_as_int(e[i]));
}

// ---------------------------------------------------------------------------
// K4: per-node gather-reduce. One node per 256-thread block; 4 waves split
// the node's edge list (shorter dependent chains), LDS combine at the end.
// 2 feats per lane. Writes MEANS directly.
// ---------------------------------------------------------------------------
__global__ void aggregate(const float* __restrict__ h, const int2* __restrict__ eidx,
                          const int* __restrict__ offsets,
                          float* __restrict__ mean_p, float* __restrict__ mean_u,
                          int n_nodes) {
    __shared__ float4 red[4][64];
    const int node = blockIdx.x;
    const int wave = threadIdx.x >> 6, lane = threadIdx.x & 63;
    const int beg = offsets[node], end = offsets[node + 1];
    float2 su = make_float2(0.f, 0.f), sp = make_float2(0.f, 0.f);
    const float* hp = h + lane * 2;

    int j = beg + wave;
    // unroll 2: two independent edge loads in flight
    for (; j + 4 < end; j += 8) {
        const int2 e0 = eidx[j];
        const int2 e1 = eidx[j + 4];
        const float2 h0 = *(const float2*)(hp + (size_t)e0.x * NFEAT);
        const float2 h1 = *(const float2*)(hp + (size_t)e1.x * NFEAT);
        const float ev0 = __int_as_float(e0.y), ev1 = __int_as_float(e1.y);
        su.x += h0.x + h1.x;
        su.y += h0.y + h1.y;
        sp.x += ev0 * h0.x + ev1 * h1.x;
        sp.y += ev0 * h0.y + ev1 * h1.y;
    }
    if (j < end) {
        const int2 e0 = eidx[j];
        const float2 h0 = *(const float2*)(hp + (size_t)e0.x * NFEAT);
        const float ev0 = __int_as_float(e0.y);
        su.x += h0.x; su.y += h0.y;
        sp.x += ev0 * h0.x; sp.y += ev0 * h0.y;
    }
    red[wave][lane] = make_float4(su.x, su.y, sp.x, sp.y);
    __syncthreads();
    if (threadIdx.x < 64) {
        const float4 a = red[0][lane], b = red[1][lane];
        const float4 c = red[2][lane], d = red[3][lane];
        const float inv = 1.0f / fmaxf((float)(end - beg), 1.0f);
        const float ux = (a.x + b.x + c.x + d.x) * inv;
        const float uy = (a.y + b.y + c.y + d.y) * inv;
        const float px = (a.z + b.z + c.z + d.z) * inv;
        const float py = (a.w + b.w + c.w + d.w) * inv;
        *(float2*)(mean_u + (size_t)node * NFEAT + lane * 2) = make_float2(ux, uy);
        *(float2*)(mean_p + (size_t)node * NFEAT + lane * 2) = make_float2(px, py);
    }
}

// ---------------------------------------------------------------------------
// K5: fused GEMM: out[n][o] = btot[o] + sum_{r<384} X[n][r] * Wcat[r][o]
// where X = [h | mean_p | mean_u].  256 threads; thread = (og 0..31)x(ng 0..7);
// each thread: 2 nodes x 4 outputs, float4 LDS reads, W k-tile staged in LDS.
// mean_u aliases out: all staging happens before any write (writes at end,
// each block writes only its own rows).
// ---------------------------------------------------------------------------
__global__ __launch_bounds__(256) void fused_gemm(
        const float* __restrict__ h, const float* __restrict__ mean_p,
        const float* mean_u, const float* __restrict__ Wcat,
        const float* __restrict__ btot, float* out, int n_nodes) {
    __shared__ float Xs[3][NPB][NFEAT];   // 24 KB
    __shared__ float Wt[32][NFEAT];       // 16 KB
    const int tid = threadIdx.x;
    const int og = tid & 31;
    const int ng = tid >> 5;
    const int o4 = og * 4;
    const int n0 = blockIdx.x * NPB;

    // stage X tiles (coalesced float4), 2 iters per source array
    {
        const float* p;
        #pragma unroll
        for (int s = 0; s < 3; ++s) {
            p = (s == 0) ? h : (s == 1) ? mean_p : mean_u;
            for (int idx = tid; idx < NPB * (NFEAT / 4); idx += 256) {
                const int n = idx >> 5;          // 32 float4 per row
                const int c4 = idx & 31;
                const int gn = n0 + n;
                float4 v = make_float4(0.f, 0.f, 0.f, 0.f);
                if (gn < n_nodes) v = *(const float4*)(p + (size_t)gn * NFEAT + c4 * 4);
                *(float4*)(&Xs[s][n][c4 * 4]) = v;
            }
        }
    }

    float acc0[4] = {0.f, 0.f, 0.f, 0.f};
    float acc1[4] = {0.f, 0.f, 0.f, 0.f};
    const int nA = ng * 2, nB = ng * 2 + 1;

    for (int kt = 0; kt < 3 * NFEAT; kt += 32) {
        __syncthreads();  // X staged (first iter) / prev Wt reads done
        for (int idx = tid; idx < 32 * (NFEAT / 4); idx += 256) {
            const int r = idx >> 5;
            const int c4 = idx & 31;
            *(float4*)(&Wt[r][c4 * 4]) =
                *(const float4*)(Wcat + (size_t)(kt + r) * NFEAT + c4 * 4);
        }
        __syncthreads();
        const int s  = kt >> 7;
        const int kb = kt & 127;
        #pragma unroll
        for (int kk = 0; kk < 32; kk += 4) {
            const float4 xa = *(const float4*)(&Xs[s][nA][kb + kk]);
            const float4 xb = *(const float4*)(&Xs[s][nB][kb + kk]);
            const float4 w0 = *(const float4*)(&Wt[kk + 0][o4]);
            const float4 w1 = *(const float4*)(&Wt[kk + 1][o4]);
            const float4 w2 = *(const float4*)(&Wt[kk + 2][o4]);
            const float4 w3 = *(const float4*)(&Wt[kk + 3][o4]);
            acc0[0] += xa.x*w0.x + xa.y*w1.x + xa.z*w2.x + xa.w*w3.x;
            acc0[1] += xa.x*w0.y + xa.y*w1.y + xa.z*w2.y + xa.w*w3.y;
            acc0[2] += xa.x*w0.z + xa.y*w1.z + xa.z*w2.z + xa.w*w3.z;
            acc0[3] += xa.x*w0.w + xa.y*w1.w + xa.z*w2.w + xa.w*w3.w;
            acc1[0] += xb.x*w0.x + xb.y*w1.x + xb.z*w2.x + xb.w*w3.x;
            acc1[1] += xb.x*w0.y + xb.y*w1.y + xb.z*w2.y + xb.w*w3.y;
            acc1[2] += xb.x*w0.z + xb.y*w1.z + xb.z*w2.z + xb.w*w3.z;
            acc1[3] += xb.x*w0.w + xb.y*w1.w + xb.z*w2.w + xb.w*w3.w;
        }
    }

    const float4 bt = *(const float4*)(btot + o4);
    if (n0 + nA < n_nodes) {
        float4 v = make_float4(acc0[0] + bt.x, acc0[1] + bt.y,
                               acc0[2] + bt.z, acc0[3] + bt.w);
        *(float4*)(out + (size_t)(n0 + nA) * NFEAT + o4) = v;
    }
    if (n0 + nB < n_nodes) {
        float4 v = make_float4(acc1[0] + bt.x, acc1[1] + bt.y,
                               acc1[2] + bt.z, acc1[3] + bt.w);
        *(float4*)(out + (size_t)(n0 + nB) * NFEAT + o4) = v;
    }
}

extern "C" void kernel_launch(void* const* d_in, const int* in_sizes, int n_in,
                              void* d_out, int out_size, void* d_ws, size_t ws_size,
                              hipStream_t stream) {
    const float* h     = (const float*)d_in[0];
    const float* e     = (const float*)d_in[1];
    const int*   src   = (const int*)d_in[2];
    const int*   dst   = (const int*)d_in[3];
    const float* Ws_w  = (const float*)d_in[4];
    const float* Ws_b  = (const float*)d_in[5];
    const float* Wn_w  = (const float*)d_in[6];
    const float* Wn_b  = (const float*)d_in[7];
    const float* Wu_w  = (const float*)d_in[8];
    const float* Wu_b  = (const float*)d_in[9];
    const float* lin_w = (const float*)d_in[10];
    const float* lin_b = (const float*)d_in[11];
    float* out = (float*)d_out;

    const int n_nodes = in_sizes[0] / NFEAT;
    const int n_edges = in_sizes[2];

    // ---- workspace layout ----
    char* ws = (char*)d_ws;
    float* mean_p = (float*)ws;                 ws += (size_t)n_nodes * NFEAT * 4;
    float* Wcat   = (float*)ws;                 ws += 3 * NFEAT * NFEAT * 4;
    float* btot   = (float*)ws;                 ws += NFEAT * 4;
    int2*  eidx   = (int2*)ws;                  ws += (size_t)n_edges * 8;
    int*   cnt    = (int*)ws;                   ws += n_nodes * 4;
    int*   offs   = (int*)ws;                   ws += (n_nodes + 1) * 4;
    int*   cursor = (int*)ws;                   ws += n_nodes * 4;
    float* mean_u = out;  // reuse d_out as scratch (see fused_gemm note)

    hipMemsetAsync(cnt, 0, (size_t)n_nodes * 4, stream);

    const int edge_blocks = (n_edges + 255) / 256;
    prep<<<NFEAT + edge_blocks, 256, 0, stream>>>(Ws_w, Wn_w, Wu_w, Ws_b, Wn_b, Wu_b,
                                                  lin_w, lin_b, dst, cnt, n_edges,
                                                  Wcat, btot);

    scan_offsets<<<1, 1024, 0, stream>>>(cnt, offs, cursor, n_nodes, n_edges);

    scatter_edges<<<edge_blocks, 256, 0, stream>>>(src, dst, e, cursor, eidx, n_edges);

    aggregate<<<n_nodes, 256, 0, stream>>>(h, eidx, offs, mean_p, mean_u, n_nodes);

    const int n_blocks = (n_nodes + NPB - 1) / NPB;
    fused_gemm<<<n_blocks, 256, 0, stream>>>(h, mean_p, mean_u, Wcat, btot,
                                             out, n_nodes);
}

// Round 4
// 191.899 us; speedup vs baseline: 6.3078x; 1.2938x over previous
//
#include <hip/hip_runtime.h>
#include <hip/hip_bf16.h>

#define NFEAT 128
#define NPB 16     // nodes per block in fused_gemm
#define CHUNK 256  // edges staged in LDS per iteration in aggregate

// ---------------------------------------------------------------------------
// K1 "prep": blocks [0,128) fuse weights into Wcat[384][128] (k-major) and
// btot; blocks [128,..) count degrees AND record each edge's rank within its
// destination node (rank[i] = old count). One atomic pass total.
// ---------------------------------------------------------------------------
__global__ void prep(const float* __restrict__ Ws, const float* __restrict__ Wn,
                     const float* __restrict__ Wu,
                     const float* __restrict__ Wsb, const float* __restrict__ Wnb,
                     const float* __restrict__ Wub,
                     const float* __restrict__ lin, const float* __restrict__ linb,
                     const int* __restrict__ dst, int* __restrict__ cnt,
                     int* __restrict__ rank, int n_edges,
                     float* __restrict__ Wcat, float* __restrict__ btot) {
    if (blockIdx.x < NFEAT) {
        __shared__ float cs[NFEAT], cn[NFEAT], cu[NFEAT], bsum[NFEAT];
        const int i = blockIdx.x;   // k index
        const int o = threadIdx.x;  // only o<128 active
        if (o < NFEAT) {
            cs[o] = Ws[o * NFEAT + i];
            cn[o] = Wn[o * NFEAT + i];
            cu[o] = Wu[o * NFEAT + i];
            bsum[o] = Wsb[o] + Wnb[o] + Wub[o];
        }
        __syncthreads();
        if (o < NFEAT) {
            float a1 = 0.f, a2 = 0.f, a3 = 0.f, ab = 0.f;
            #pragma unroll 4
            for (int k = 0; k < NFEAT; ++k) {
                const float l = lin[o * NFEAT + k];
                a1 += l * cs[k];
                a2 += l * cn[k];
                a3 += l * cu[k];
                ab += l * bsum[k];
            }
            Wcat[(0 * NFEAT + i) * NFEAT + o] = a1;
            Wcat[(1 * NFEAT + i) * NFEAT + o] = a2;
            Wcat[(2 * NFEAT + i) * NFEAT + o] = a3;
            if (i == 0) btot[o] = ab + linb[o];
        }
    } else {
        const int i = (blockIdx.x - NFEAT) * 256 + threadIdx.x;
        if (i < n_edges) rank[i] = atomicAdd(&cnt[dst[i]], 1);
    }
}

// ---------------------------------------------------------------------------
// K2: exclusive prefix scan (single block of 1024 = 16 waves, shfl-based).
// ---------------------------------------------------------------------------
__global__ void scan_offsets(const int* __restrict__ cnt, int* __restrict__ offsets,
                             int n_nodes, int n_edges) {
    __shared__ int wbase_s[16];
    __shared__ int wsum[16];
    const int t = threadIdx.x;
    const int wave = t >> 6, lane = t & 63;
    const int chunk = (n_nodes + 1023) >> 10;
    const int b = t * chunk;
    int s = 0;
    for (int i = 0; i < chunk; ++i) {
        const int idx = b + i;
        if (idx < n_nodes) s += cnt[idx];
    }
    int incl = s;
    #pragma unroll
    for (int d = 1; d < 64; d <<= 1) {
        const int v = __shfl_up(incl, d);
        if (lane >= d) incl += v;
    }
    if (lane == 63) wsum[wave] = incl;
    __syncthreads();
    if (t == 0) {
        int run = 0;
        for (int w = 0; w < 16; ++w) { wbase_s[w] = run; run += wsum[w]; }
    }
    __syncthreads();
    int run = wbase_s[wave] + (incl - s);  // exclusive prefix for this thread
    for (int i = 0; i < chunk; ++i) {
        const int idx = b + i;
        if (idx < n_nodes) {
            offsets[idx] = run;
            run += cnt[idx];
        }
    }
    if (t == 0) offsets[n_nodes] = n_edges;
}

// ---------------------------------------------------------------------------
// K3: scatter edges into precomputed CSR slots (NO atomics): pure stores.
// ---------------------------------------------------------------------------
__global__ void scatter_edges(const int* __restrict__ src, const int* __restrict__ dst,
                              const float* __restrict__ e, const int* __restrict__ offs,
                              const int* __restrict__ rank, int2* __restrict__ eidx,
                              int n_edges) {
    const int i = blockIdx.x * blockDim.x + threadIdx.x;
    if (i >= n_edges) return;
    const int pos = offs[dst[i]] + rank[i];
    eidx[pos] = make_int2(src[i], __float_as_int(e[i]));
}

// ---------------------------------------------------------------------------
// K4: per-node gather-reduce. One node per 256-thread block.
// Edge list staged in LDS (kills per-edge global broadcast loads).
// Half-wave (32 lanes) loads one full h row as float4 (32x16B = 512B).
// 8 half-waves x unroll-4 = up to 32 gathers in flight per block.
// Writes MEANS directly.
// ---------------------------------------------------------------------------
__global__ __launch_bounds__(256) void aggregate(
        const float* __restrict__ h, const int2* __restrict__ eidx,
        const int* __restrict__ offsets,
        float* __restrict__ mean_p, float* __restrict__ mean_u, int n_nodes) {
    __shared__ int2 se[CHUNK];
    __shared__ float4 red_u[8][32];
    __shared__ float4 red_p[8][32];
    const int node = blockIdx.x;
    const int tid  = threadIdx.x;
    const int hw   = tid >> 5;   // half-wave id 0..7
    const int hl   = tid & 31;   // lane in half-wave
    const int beg = offsets[node], end = offsets[node + 1];
    const int deg = end - beg;
    float4 su = make_float4(0.f, 0.f, 0.f, 0.f);
    float4 sp = make_float4(0.f, 0.f, 0.f, 0.f);
    const float* hp = h + hl * 4;

    for (int cs = beg; cs < end; cs += CHUNK) {
        const int cnt = min(CHUNK, end - cs);
        __syncthreads();  // protect se from previous iteration's readers
        if (tid < cnt) se[tid] = eidx[cs + tid];
        __syncthreads();
        int j = hw;
        for (; j + 24 < cnt; j += 32) {
            const int2 e0 = se[j], e1 = se[j + 8], e2 = se[j + 16], e3 = se[j + 24];
            const float4 h0 = *(const float4*)(hp + (size_t)e0.x * NFEAT);
            const float4 h1 = *(const float4*)(hp + (size_t)e1.x * NFEAT);
            const float4 h2 = *(const float4*)(hp + (size_t)e2.x * NFEAT);
            const float4 h3 = *(const float4*)(hp + (size_t)e3.x * NFEAT);
            const float v0 = __int_as_float(e0.y), v1 = __int_as_float(e1.y);
            const float v2 = __int_as_float(e2.y), v3 = __int_as_float(e3.y);
            su.x += h0.x + h1.x + h2.x + h3.x;
            su.y += h0.y + h1.y + h2.y + h3.y;
            su.z += h0.z + h1.z + h2.z + h3.z;
            su.w += h0.w + h1.w + h2.w + h3.w;
            sp.x += v0 * h0.x + v1 * h1.x + v2 * h2.x + v3 * h3.x;
            sp.y += v0 * h0.y + v1 * h1.y + v2 * h2.y + v3 * h3.y;
            sp.z += v0 * h0.z + v1 * h1.z + v2 * h2.z + v3 * h3.z;
            sp.w += v0 * h0.w + v1 * h1.w + v2 * h2.w + v3 * h3.w;
        }
        for (; j < cnt; j += 8) {
            const int2 e0 = se[j];
            const float4 h0 = *(const float4*)(hp + (size_t)e0.x * NFEAT);
            const float v0 = __int_as_float(e0.y);
            su.x += h0.x; su.y += h0.y; su.z += h0.z; su.w += h0.w;
            sp.x += v0 * h0.x; sp.y += v0 * h0.y;
            sp.z += v0 * h0.z; sp.w += v0 * h0.w;
        }
    }
    red_u[hw][hl] = su;
    red_p[hw][hl] = sp;
    __syncthreads();
    if (tid < 64) {
        const int which = tid >> 5;   // 0: mean_u, 1: mean_p
        const int l = tid & 31;
        const float4 (*red)[32] = which ? red_p : red_u;
        float4 a = make_float4(0.f, 0.f, 0.f, 0.f);
        #pragma unroll
        for (int w = 0; w < 8; ++w) {
            const float4 t = red[w][l];
            a.x += t.x; a.y += t.y; a.z += t.z; a.w += t.w;
        }
        const float inv = 1.0f / fmaxf((float)deg, 1.0f);
        a.x *= inv; a.y *= inv; a.z *= inv; a.w *= inv;
        float* dp = (which ? mean_p : mean_u) + (size_t)node * NFEAT + l * 4;
        *(float4*)dp = a;
    }
}

// ---------------------------------------------------------------------------
// K5: fused GEMM: out[n][o] = btot[o] + sum_{r<384} X[n][r] * Wcat[r][o]
// where X = [h | mean_p | mean_u].  mean_u aliases out: all X staging happens
// before any write; each block writes only its own rows.
// ---------------------------------------------------------------------------
__global__ __launch_bounds__(256) void fused_gemm(
        const float* __restrict__ h, const float* __restrict__ mean_p,
        const float* mean_u, const float* __restrict__ Wcat,
        const float* __restrict__ btot, float* out, int n_nodes) {
    __shared__ float Xs[3][NPB][NFEAT];   // 24 KB
    __shared__ float Wt[32][NFEAT];       // 16 KB
    const int tid = threadIdx.x;
    const int og = tid & 31;
    const int ng = tid >> 5;
    const int o4 = og * 4;
    const int n0 = blockIdx.x * NPB;

    {
        const float* p;
        #pragma unroll
        for (int s = 0; s < 3; ++s) {
            p = (s == 0) ? h : (s == 1) ? mean_p : mean_u;
            for (int idx = tid; idx < NPB * (NFEAT / 4); idx += 256) {
                const int n = idx >> 5;
                const int c4 = idx & 31;
                const int gn = n0 + n;
                float4 v = make_float4(0.f, 0.f, 0.f, 0.f);
                if (gn < n_nodes) v = *(const float4*)(p + (size_t)gn * NFEAT + c4 * 4);
                *(float4*)(&Xs[s][n][c4 * 4]) = v;
            }
        }
    }

    float acc0[4] = {0.f, 0.f, 0.f, 0.f};
    float acc1[4] = {0.f, 0.f, 0.f, 0.f};
    const int nA = ng * 2, nB = ng * 2 + 1;

    for (int kt = 0; kt < 3 * NFEAT; kt += 32) {
        __syncthreads();
        for (int idx = tid; idx < 32 * (NFEAT / 4); idx += 256) {
            const int r = idx >> 5;
            const int c4 = idx & 31;
            *(float4*)(&Wt[r][c4 * 4]) =
                *(const float4*)(Wcat + (size_t)(kt + r) * NFEAT + c4 * 4);
        }
        __syncthreads();
        const int s  = kt >> 7;
        const int kb = kt & 127;
        #pragma unroll
        for (int kk = 0; kk < 32; kk += 4) {
            const float4 xa = *(const float4*)(&Xs[s][nA][kb + kk]);
            const float4 xb = *(const float4*)(&Xs[s][nB][kb + kk]);
            const float4 w0 = *(const float4*)(&Wt[kk + 0][o4]);
            const float4 w1 = *(const float4*)(&Wt[kk + 1][o4]);
            const float4 w2 = *(const float4*)(&Wt[kk + 2][o4]);
            const float4 w3 = *(const float4*)(&Wt[kk + 3][o4]);
            acc0[0] += xa.x*w0.x + xa.y*w1.x + xa.z*w2.x + xa.w*w3.x;
            acc0[1] += xa.x*w0.y + xa.y*w1.y + xa.z*w2.y + xa.w*w3.y;
            acc0[2] += xa.x*w0.z + xa.y*w1.z + xa.z*w2.z + xa.w*w3.z;
            acc0[3] += xa.x*w0.w + xa.y*w1.w + xa.z*w2.w + xa.w*w3.w;
            acc1[0] += xb.x*w0.x + xb.y*w1.x + xb.z*w2.x + xb.w*w3.x;
            acc1[1] += xb.x*w0.y + xb.y*w1.y + xb.z*w2.y + xb.w*w3.y;
            acc1[2] += xb.x*w0.z + xb.y*w1.z + xb.z*w2.z + xb.w*w3.z;
            acc1[3] += xb.x*w0.w + xb.y*w1.w + xb.z*w2.w + xb.w*w3.w;
        }
    }

    const float4 bt = *(const float4*)(btot + o4);
    if (n0 + nA < n_nodes) {
        float4 v = make_float4(acc0[0] + bt.x, acc0[1] + bt.y,
                               acc0[2] + bt.z, acc0[3] + bt.w);
        *(float4*)(out + (size_t)(n0 + nA) * NFEAT + o4) = v;
    }
    if (n0 + nB < n_nodes) {
        float4 v = make_float4(acc1[0] + bt.x, acc1[1] + bt.y,
                               acc1[2] + bt.z, acc1[3] + bt.w);
        *(float4*)(out + (size_t)(n0 + nB) * NFEAT + o4) = v;
    }
}

extern "C" void kernel_launch(void* const* d_in, const int* in_sizes, int n_in,
                              void* d_out, int out_size, void* d_ws, size_t ws_size,
                              hipStream_t stream) {
    const float* h     = (const float*)d_in[0];
    const float* e     = (const float*)d_in[1];
    const int*   src   = (const int*)d_in[2];
    const int*   dst   = (const int*)d_in[3];
    const float* Ws_w  = (const float*)d_in[4];
    const float* Ws_b  = (const float*)d_in[5];
    const float* Wn_w  = (const float*)d_in[6];
    const float* Wn_b  = (const float*)d_in[7];
    const float* Wu_w  = (const float*)d_in[8];
    const float* Wu_b  = (const float*)d_in[9];
    const float* lin_w = (const float*)d_in[10];
    const float* lin_b = (const float*)d_in[11];
    float* out = (float*)d_out;

    const int n_nodes = in_sizes[0] / NFEAT;
    const int n_edges = in_sizes[2];

    // ---- workspace layout ----
    char* ws = (char*)d_ws;
    float* mean_p = (float*)ws;                 ws += (size_t)n_nodes * NFEAT * 4;
    float* Wcat   = (float*)ws;                 ws += 3 * NFEAT * NFEAT * 4;
    float* btot   = (float*)ws;                 ws += NFEAT * 4;
    int2*  eidx   = (int2*)ws;                  ws += (size_t)n_edges * 8;
    int*   cnt    = (int*)ws;                   ws += n_nodes * 4;
    int*   offs   = (int*)ws;                   ws += (n_nodes + 1) * 4;
    // rank overlays mean_p: rank is dead after scatter_edges; mean_p is first
    // written by aggregate (which runs after scatter_edges on the same stream).
    int*   rank   = (int*)mean_p;
    float* mean_u = out;  // reuse d_out as scratch (see fused_gemm note)

    hipMemsetAsync(cnt, 0, (size_t)n_nodes * 4, stream);

    const int edge_blocks = (n_edges + 255) / 256;
    prep<<<NFEAT + edge_blocks, 256, 0, stream>>>(Ws_w, Wn_w, Wu_w, Ws_b, Wn_b, Wu_b,
                                                  lin_w, lin_b, dst, cnt, rank,
                                                  n_edges, Wcat, btot);

    scan_offsets<<<1, 1024, 0, stream>>>(cnt, offs, n_nodes, n_edges);

    scatter_edges<<<edge_blocks, 256, 0, stream>>>(src, dst, e, offs, rank,
                                                   eidx, n_edges);

    aggregate<<<n_nodes, 256, 0, stream>>>(h, eidx, offs, mean_p, mean_u, n_nodes);

    const int n_blocks = (n_nodes + NPB - 1) / NPB;
    fused_gemm<<<n_blocks, 256, 0, stream>>>(h, mean_p, mean_u, Wcat, btot,
                                             out, n_nodes);
}

// Round 5
// 170.567 us; speedup vs baseline: 7.0967x; 1.1251x over previous
//
#include <hip/hip_runtime.h>
#include <hip/hip_bf16.h>

#define NFEAT 128
#define NPB 16     // nodes per block in fused_gemm
#define CHUNK 256  // edges staged in LDS per iteration in aggregate
#define P 64       // histogram blocks (must be <= 64 so hist+base fit in mean_p)
#define MAXN 10240 // LDS histogram capacity (n_nodes must be <= this)

// ---------------------------------------------------------------------------
// K-A: blocks [0,P): per-block LDS histogram of dst over this block's edge
// slice -> hist[b*n_nodes + node].  blocks [P, P+128): fuse weights into
// Wcat[384][128] (k-major) and btot.  No global atomics anywhere.
// ---------------------------------------------------------------------------
__global__ __launch_bounds__(256) void hist_weights(
        const int* __restrict__ dst, int* __restrict__ hist, int n_edges,
        int n_nodes,
        const float* __restrict__ Ws, const float* __restrict__ Wn,
        const float* __restrict__ Wu,
        const float* __restrict__ Wsb, const float* __restrict__ Wnb,
        const float* __restrict__ Wub,
        const float* __restrict__ lin, const float* __restrict__ linb,
        float* __restrict__ Wcat, float* __restrict__ btot) {
    __shared__ int lh[MAXN];
    __shared__ float cs[NFEAT], cn[NFEAT], cu[NFEAT], bsum[NFEAT];
    const int tid = threadIdx.x;
    if (blockIdx.x < P) {
        const int b = blockIdx.x;
        for (int n = tid; n < n_nodes; n += 256) lh[n] = 0;
        __syncthreads();
        const int per = (n_edges + P - 1) / P;
        const int beg = b * per;
        const int end = min(beg + per, n_edges);
        for (int i = beg + tid * 4; i < end; i += 1024) {
            if (i + 4 <= end) {
                const int4 d4 = *(const int4*)(dst + i);
                atomicAdd(&lh[d4.x], 1);
                atomicAdd(&lh[d4.y], 1);
                atomicAdd(&lh[d4.z], 1);
                atomicAdd(&lh[d4.w], 1);
            } else {
                for (int k = i; k < end; ++k) atomicAdd(&lh[dst[k]], 1);
            }
        }
        __syncthreads();
        for (int n = tid; n < n_nodes; n += 256)
            hist[(size_t)b * n_nodes + n] = lh[n];
    } else {
        const int i = blockIdx.x - P;   // k index 0..127
        const int o = tid;              // only o<128 active
        if (o < NFEAT) {
            cs[o] = Ws[o * NFEAT + i];
            cn[o] = Wn[o * NFEAT + i];
            cu[o] = Wu[o * NFEAT + i];
            bsum[o] = Wsb[o] + Wnb[o] + Wub[o];
        }
        __syncthreads();
        if (o < NFEAT) {
            float a1 = 0.f, a2 = 0.f, a3 = 0.f, ab = 0.f;
            #pragma unroll 4
            for (int k = 0; k < NFEAT; ++k) {
                const float l = lin[o * NFEAT + k];
                a1 += l * cs[k];
                a2 += l * cn[k];
                a3 += l * cu[k];
                ab += l * bsum[k];
            }
            Wcat[(0 * NFEAT + i) * NFEAT + o] = a1;
            Wcat[(1 * NFEAT + i) * NFEAT + o] = a2;
            Wcat[(2 * NFEAT + i) * NFEAT + o] = a3;
            if (i == 0) btot[o] = ab + linb[o];
        }
    }
}

// ---------------------------------------------------------------------------
// K-B: column scan. One lane per node; serial prefix over the P block
// histograms: base[b][node] = sum_{b'<b} hist[b'][node]; cnt[node] = total.
// All loads/stores coalesced (consecutive lanes -> consecutive nodes).
// ---------------------------------------------------------------------------
__global__ void col_scan(const int* __restrict__ hist, int* __restrict__ base,
                         int* __restrict__ cnt, int n_nodes) {
    const int node = blockIdx.x * blockDim.x + threadIdx.x;
    if (node >= n_nodes) return;
    int run = 0;
    #pragma unroll 8
    for (int b = 0; b < P; ++b) {
        const int h = hist[(size_t)b * n_nodes + node];
        base[(size_t)b * n_nodes + node] = run;
        run += h;
    }
    cnt[node] = run;
}

// ---------------------------------------------------------------------------
// K-C: exclusive prefix scan of cnt -> offsets (single block, shfl-based).
// ---------------------------------------------------------------------------
__global__ void scan_offsets(const int* __restrict__ cnt, int* __restrict__ offsets,
                             int n_nodes, int n_edges) {
    __shared__ int wbase_s[16];
    __shared__ int wsum[16];
    const int t = threadIdx.x;
    const int wave = t >> 6, lane = t & 63;
    const int chunk = (n_nodes + 1023) >> 10;
    const int b = t * chunk;
    int s = 0;
    for (int i = 0; i < chunk; ++i) {
        const int idx = b + i;
        if (idx < n_nodes) s += cnt[idx];
    }
    int incl = s;
    #pragma unroll
    for (int d = 1; d < 64; d <<= 1) {
        const int v = __shfl_up(incl, d);
        if (lane >= d) incl += v;
    }
    if (lane == 63) wsum[wave] = incl;
    __syncthreads();
    if (t == 0) {
        int run = 0;
        for (int w = 0; w < 16; ++w) { wbase_s[w] = run; run += wsum[w]; }
    }
    __syncthreads();
    int run = wbase_s[wave] + (incl - s);
    for (int i = 0; i < chunk; ++i) {
        const int idx = b + i;
        if (idx < n_nodes) {
            offsets[idx] = run;
            run += cnt[idx];
        }
    }
    if (t == 0) offsets[n_nodes] = n_edges;
}

// ---------------------------------------------------------------------------
// K-D: scatter into CSR slots via LDS cursors (no global atomics).
// lh[n] = offs[n] + base[b][n]; pos = LDS atomicAdd(lh[dst]).
// ---------------------------------------------------------------------------
__global__ __launch_bounds__(256) void scatter_csr(
        const int* __restrict__ src, const int* __restrict__ dst,
        const float* __restrict__ e, const int* __restrict__ offs,
        const int* __restrict__ base, int2* __restrict__ eidx,
        int n_edges, int n_nodes) {
    __shared__ int lh[MAXN];
    const int tid = threadIdx.x;
    const int b = blockIdx.x;
    for (int n = tid; n < n_nodes; n += 256)
        lh[n] = offs[n] + base[(size_t)b * n_nodes + n];
    __syncthreads();
    const int per = (n_edges + P - 1) / P;
    const int beg = b * per;
    const int end = min(beg + per, n_edges);
    for (int i = beg + tid * 4; i < end; i += 1024) {
        if (i + 4 <= end) {
            const int4 d4 = *(const int4*)(dst + i);
            const int4 s4 = *(const int4*)(src + i);
            const float4 e4 = *(const float4*)(e + i);
            int p0 = atomicAdd(&lh[d4.x], 1);
            int p1 = atomicAdd(&lh[d4.y], 1);
            int p2 = atomicAdd(&lh[d4.z], 1);
            int p3 = atomicAdd(&lh[d4.w], 1);
            eidx[p0] = make_int2(s4.x, __float_as_int(e4.x));
            eidx[p1] = make_int2(s4.y, __float_as_int(e4.y));
            eidx[p2] = make_int2(s4.z, __float_as_int(e4.z));
            eidx[p3] = make_int2(s4.w, __float_as_int(e4.w));
        } else {
            for (int k = i; k < end; ++k) {
                const int pos = atomicAdd(&lh[dst[k]], 1);
                eidx[pos] = make_int2(src[k], __float_as_int(e[k]));
            }
        }
    }
}

// ---------------------------------------------------------------------------
// K-E: per-node gather-reduce. One node per 256-thread block.
// Edge list staged in LDS; half-wave float4 row loads; writes MEANS.
// ---------------------------------------------------------------------------
__global__ __launch_bounds__(256) void aggregate(
        const float* __restrict__ h, const int2* __restrict__ eidx,
        const int* __restrict__ offsets,
        float* __restrict__ mean_p, float* __restrict__ mean_u, int n_nodes) {
    __shared__ int2 se[CHUNK];
    __shared__ float4 red_u[8][32];
    __shared__ float4 red_p[8][32];
    const int node = blockIdx.x;
    const int tid  = threadIdx.x;
    const int hw   = tid >> 5;
    const int hl   = tid & 31;
    const int beg = offsets[node], end = offsets[node + 1];
    const int deg = end - beg;
    float4 su = make_float4(0.f, 0.f, 0.f, 0.f);
    float4 sp = make_float4(0.f, 0.f, 0.f, 0.f);
    const float* hp = h + hl * 4;

    for (int cs = beg; cs < end; cs += CHUNK) {
        const int cnt = min(CHUNK, end - cs);
        __syncthreads();
        if (tid < cnt) se[tid] = eidx[cs + tid];
        __syncthreads();
        int j = hw;
        for (; j + 24 < cnt; j += 32) {
            const int2 e0 = se[j], e1 = se[j + 8], e2 = se[j + 16], e3 = se[j + 24];
            const float4 h0 = *(const float4*)(hp + (size_t)e0.x * NFEAT);
            const float4 h1 = *(const float4*)(hp + (size_t)e1.x * NFEAT);
            const float4 h2 = *(const float4*)(hp + (size_t)e2.x * NFEAT);
            const float4 h3 = *(const float4*)(hp + (size_t)e3.x * NFEAT);
            const float v0 = __int_as_float(e0.y), v1 = __int_as_float(e1.y);
            const float v2 = __int_as_float(e2.y), v3 = __int_as_float(e3.y);
            su.x += h0.x + h1.x + h2.x + h3.x;
            su.y += h0.y + h1.y + h2.y + h3.y;
            su.z += h0.z + h1.z + h2.z + h3.z;
            su.w += h0.w + h1.w + h2.w + h3.w;
            sp.x += v0 * h0.x + v1 * h1.x + v2 * h2.x + v3 * h3.x;
            sp.y += v0 * h0.y + v1 * h1.y + v2 * h2.y + v3 * h3.y;
            sp.z += v0 * h0.z + v1 * h1.z + v2 * h2.z + v3 * h3.z;
            sp.w += v0 * h0.w + v1 * h1.w + v2 * h2.w + v3 * h3.w;
        }
        for (; j < cnt; j += 8) {
            const int2 e0 = se[j];
            const float4 h0 = *(const float4*)(hp + (size_t)e0.x * NFEAT);
            const float v0 = __int_as_float(e0.y);
            su.x += h0.x; su.y += h0.y; su.z += h0.z; su.w += h0.w;
            sp.x += v0 * h0.x; sp.y += v0 * h0.y;
            sp.z += v0 * h0.z; sp.w += v0 * h0.w;
        }
    }
    red_u[hw][hl] = su;
    red_p[hw][hl] = sp;
    __syncthreads();
    if (tid < 64) {
        const int which = tid >> 5;
        const int l = tid & 31;
        const float4 (*red)[32] = which ? red_p : red_u;
        float4 a = make_float4(0.f, 0.f, 0.f, 0.f);
        #pragma unroll
        for (int w = 0; w < 8; ++w) {
            const float4 t = red[w][l];
            a.x += t.x; a.y += t.y; a.z += t.z; a.w += t.w;
        }
        const float inv = 1.0f / fmaxf((float)deg, 1.0f);
        a.x *= inv; a.y *= inv; a.z *= inv; a.w *= inv;
        float* dp = (which ? mean_p : mean_u) + (size_t)node * NFEAT + l * 4;
        *(float4*)dp = a;
    }
}

// ---------------------------------------------------------------------------
// K-F: fused GEMM: out[n][o] = btot[o] + sum_{r<384} X[n][r] * Wcat[r][o],
// X = [h | mean_p | mean_u].  mean_u aliases out (staged before any write).
// ---------------------------------------------------------------------------
__global__ __launch_bounds__(256) void fused_gemm(
        const float* __restrict__ h, const float* __restrict__ mean_p,
        const float* mean_u, const float* __restrict__ Wcat,
        const float* __restrict__ btot, float* out, int n_nodes) {
    __shared__ float Xs[3][NPB][NFEAT];
    __shared__ float Wt[32][NFEAT];
    const int tid = threadIdx.x;
    const int og = tid & 31;
    const int ng = tid >> 5;
    const int o4 = og * 4;
    const int n0 = blockIdx.x * NPB;

    {
        const float* p;
        #pragma unroll
        for (int s = 0; s < 3; ++s) {
            p = (s == 0) ? h : (s == 1) ? mean_p : mean_u;
            for (int idx = tid; idx < NPB * (NFEAT / 4); idx += 256) {
                const int n = idx >> 5;
                const int c4 = idx & 31;
                const int gn = n0 + n;
                float4 v = make_float4(0.f, 0.f, 0.f, 0.f);
                if (gn < n_nodes) v = *(const float4*)(p + (size_t)gn * NFEAT + c4 * 4);
                *(float4*)(&Xs[s][n][c4 * 4]) = v;
            }
        }
    }

    float acc0[4] = {0.f, 0.f, 0.f, 0.f};
    float acc1[4] = {0.f, 0.f, 0.f, 0.f};
    const int nA = ng * 2, nB = ng * 2 + 1;

    for (int kt = 0; kt < 3 * NFEAT; kt += 32) {
        __syncthreads();
        for (int idx = tid; idx < 32 * (NFEAT / 4); idx += 256) {
            const int r = idx >> 5;
            const int c4 = idx & 31;
            *(float4*)(&Wt[r][c4 * 4]) =
                *(const float4*)(Wcat + (size_t)(kt + r) * NFEAT + c4 * 4);
        }
        __syncthreads();
        const int s  = kt >> 7;
        const int kb = kt & 127;
        #pragma unroll
        for (int kk = 0; kk < 32; kk += 4) {
            const float4 xa = *(const float4*)(&Xs[s][nA][kb + kk]);
            const float4 xb = *(const float4*)(&Xs[s][nB][kb + kk]);
            const float4 w0 = *(const float4*)(&Wt[kk + 0][o4]);
            const float4 w1 = *(const float4*)(&Wt[kk + 1][o4]);
            const float4 w2 = *(const float4*)(&Wt[kk + 2][o4]);
            const float4 w3 = *(const float4*)(&Wt[kk + 3][o4]);
            acc0[0] += xa.x*w0.x + xa.y*w1.x + xa.z*w2.x + xa.w*w3.x;
            acc0[1] += xa.x*w0.y + xa.y*w1.y + xa.z*w2.y + xa.w*w3.y;
            acc0[2] += xa.x*w0.z + xa.y*w1.z + xa.z*w2.z + xa.w*w3.z;
            acc0[3] += xa.x*w0.w + xa.y*w1.w + xa.z*w2.w + xa.w*w3.w;
            acc1[0] += xb.x*w0.x + xb.y*w1.x + xb.z*w2.x + xb.w*w3.x;
            acc1[1] += xb.x*w0.y + xb.y*w1.y + xb.z*w2.y + xb.w*w3.y;
            acc1[2] += xb.x*w0.z + xb.y*w1.z + xb.z*w2.z + xb.w*w3.z;
            acc1[3] += xb.x*w0.w + xb.y*w1.w + xb.z*w2.w + xb.w*w3.w;
        }
    }

    const float4 bt = *(const float4*)(btot + o4);
    if (n0 + nA < n_nodes) {
        float4 v = make_float4(acc0[0] + bt.x, acc0[1] + bt.y,
                               acc0[2] + bt.z, acc0[3] + bt.w);
        *(float4*)(out + (size_t)(n0 + nA) * NFEAT + o4) = v;
    }
    if (n0 + nB < n_nodes) {
        float4 v = make_float4(acc1[0] + bt.x, acc1[1] + bt.y,
                               acc1[2] + bt.z, acc1[3] + bt.w);
        *(float4*)(out + (size_t)(n0 + nB) * NFEAT + o4) = v;
    }
}

extern "C" void kernel_launch(void* const* d_in, const int* in_sizes, int n_in,
                              void* d_out, int out_size, void* d_ws, size_t ws_size,
                              hipStream_t stream) {
    const float* h     = (const float*)d_in[0];
    const float* e     = (const float*)d_in[1];
    const int*   src   = (const int*)d_in[2];
    const int*   dst   = (const int*)d_in[3];
    const float* Ws_w  = (const float*)d_in[4];
    const float* Ws_b  = (const float*)d_in[5];
    const float* Wn_w  = (const float*)d_in[6];
    const float* Wn_b  = (const float*)d_in[7];
    const float* Wu_w  = (const float*)d_in[8];
    const float* Wu_b  = (const float*)d_in[9];
    const float* lin_w = (const float*)d_in[10];
    const float* lin_b = (const float*)d_in[11];
    float* out = (float*)d_out;

    const int n_nodes = in_sizes[0] / NFEAT;
    const int n_edges = in_sizes[2];

    // ---- workspace layout ----
    char* ws = (char*)d_ws;
    float* mean_p = (float*)ws;                 ws += (size_t)n_nodes * NFEAT * 4;
    float* Wcat   = (float*)ws;                 ws += 3 * NFEAT * NFEAT * 4;
    float* btot   = (float*)ws;                 ws += NFEAT * 4;
    int2*  eidx   = (int2*)ws;                  ws += (size_t)n_edges * 8;
    int*   cnt    = (int*)ws;                   ws += n_nodes * 4;
    int*   offs   = (int*)ws;                   ws += (n_nodes + 1) * 4;
    // hist + base (P*n_nodes ints each, 2*P <= NFEAT so they fit exactly)
    // overlay mean_p: both are dead before aggregate first writes mean_p.
    int*   hist   = (int*)mean_p;
    int*   base   = hist + (size_t)P * n_nodes;
    float* mean_u = out;  // reuse d_out as scratch (see fused_gemm note)

    hist_weights<<<P + NFEAT, 256, 0, stream>>>(dst, hist, n_edges, n_nodes,
                                                Ws_w, Wn_w, Wu_w, Ws_b, Wn_b, Wu_b,
                                                lin_w, lin_b, Wcat, btot);

    col_scan<<<(n_nodes + 255) / 256, 256, 0, stream>>>(hist, base, cnt, n_nodes);

    scan_offsets<<<1, 1024, 0, stream>>>(cnt, offs, n_nodes, n_edges);

    scatter_csr<<<P, 256, 0, stream>>>(src, dst, e, offs, base, eidx,
                                       n_edges, n_nodes);

    aggregate<<<n_nodes, 256, 0, stream>>>(h, eidx, offs, mean_p, mean_u, n_nodes);

    const int n_blocks = (n_nodes + NPB - 1) / NPB;
    fused_gemm<<<n_blocks, 256, 0, stream>>>(h, mean_p, mean_u, Wcat, btot,
                                             out, n_nodes);
}

// Round 6
// 164.276 us; speedup vs baseline: 7.3684x; 1.0383x over previous
//
#include <hip/hip_runtime.h>
#include <hip/hip_bf16.h>

#define NFEAT 128
#define NPB 16     // nodes per block in fused_gemm
#define P 64       // histogram blocks (2*P*n_nodes ints must fit in mean_p)
#define MAXN 10240 // LDS histogram capacity (n_nodes must be <= this)
#define CAP 256    // fixed per-node CSR capacity (max degree << 256)

// ---------------------------------------------------------------------------
// K-A: blocks [0,P): per-block LDS histogram of dst over this block's edge
// slice -> hist[b*n_nodes + node].  blocks [P, P+128): fuse weights into
// Wcat[384][128] (k-major) and btot.  No global atomics anywhere.
// ---------------------------------------------------------------------------
__global__ __launch_bounds__(256) void hist_weights(
        const int* __restrict__ dst, int* __restrict__ hist, int n_edges,
        int n_nodes,
        const float* __restrict__ Ws, const float* __restrict__ Wn,
        const float* __restrict__ Wu,
        const float* __restrict__ Wsb, const float* __restrict__ Wnb,
        const float* __restrict__ Wub,
        const float* __restrict__ lin, const float* __restrict__ linb,
        float* __restrict__ Wcat, float* __restrict__ btot) {
    __shared__ int lh[MAXN];
    __shared__ float cs[NFEAT], cn[NFEAT], cu[NFEAT], bsum[NFEAT];
    const int tid = threadIdx.x;
    if (blockIdx.x < P) {
        const int b = blockIdx.x;
        for (int n = tid; n < n_nodes; n += 256) lh[n] = 0;
        __syncthreads();
        const int per = (n_edges + P - 1) / P;
        const int beg = b * per;
        const int end = min(beg + per, n_edges);
        for (int i = beg + tid * 4; i < end; i += 1024) {
            if (i + 4 <= end) {
                const int4 d4 = *(const int4*)(dst + i);
                atomicAdd(&lh[d4.x], 1);
                atomicAdd(&lh[d4.y], 1);
                atomicAdd(&lh[d4.z], 1);
                atomicAdd(&lh[d4.w], 1);
            } else {
                for (int k = i; k < end; ++k) atomicAdd(&lh[dst[k]], 1);
            }
        }
        __syncthreads();
        for (int n = tid; n < n_nodes; n += 256)
            hist[(size_t)b * n_nodes + n] = lh[n];
    } else {
        const int i = blockIdx.x - P;   // k index 0..127
        const int o = tid;              // only o<128 active
        if (o < NFEAT) {
            cs[o] = Ws[o * NFEAT + i];
            cn[o] = Wn[o * NFEAT + i];
            cu[o] = Wu[o * NFEAT + i];
            bsum[o] = Wsb[o] + Wnb[o] + Wub[o];
        }
        __syncthreads();
        if (o < NFEAT) {
            float a1 = 0.f, a2 = 0.f, a3 = 0.f, ab = 0.f;
            #pragma unroll 4
            for (int k = 0; k < NFEAT; ++k) {
                const float l = lin[o * NFEAT + k];
                a1 += l * cs[k];
                a2 += l * cn[k];
                a3 += l * cu[k];
                ab += l * bsum[k];
            }
            Wcat[(0 * NFEAT + i) * NFEAT + o] = a1;
            Wcat[(1 * NFEAT + i) * NFEAT + o] = a2;
            Wcat[(2 * NFEAT + i) * NFEAT + o] = a3;
            if (i == 0) btot[o] = ab + linb[o];
        }
    }
}

// ---------------------------------------------------------------------------
// K-B: column scan. One lane per node; serial prefix over the P block
// histograms: base[b][node] = sum_{b'<b} hist[b'][node]; cnt[node] = total.
// All loads/stores coalesced.
// ---------------------------------------------------------------------------
__global__ void col_scan(const int* __restrict__ hist, int* __restrict__ base,
                         int* __restrict__ cnt, int n_nodes) {
    const int node = blockIdx.x * blockDim.x + threadIdx.x;
    if (node >= n_nodes) return;
    int run = 0;
    #pragma unroll 8
    for (int b = 0; b < P; ++b) {
        const int h = hist[(size_t)b * n_nodes + node];
        base[(size_t)b * n_nodes + node] = run;
        run += h;
    }
    cnt[node] = run;
}

// ---------------------------------------------------------------------------
// K-C: scatter into fixed-capacity CSR slots via LDS cursors (no global
// atomics, no global offsets scan): lh[n] = n*CAP + base[b][n].
// ---------------------------------------------------------------------------
__global__ __launch_bounds__(256) void scatter_csr(
        const int* __restrict__ src, const int* __restrict__ dst,
        const float* __restrict__ e, const int* __restrict__ base,
        int2* __restrict__ eidx, int n_edges, int n_nodes) {
    __shared__ int lh[MAXN];
    const int tid = threadIdx.x;
    const int b = blockIdx.x;
    for (int n = tid; n < n_nodes; n += 256)
        lh[n] = n * CAP + base[(size_t)b * n_nodes + n];
    __syncthreads();
    const int per = (n_edges + P - 1) / P;
    const int beg = b * per;
    const int end = min(beg + per, n_edges);
    for (int i = beg + tid * 4; i < end; i += 1024) {
        if (i + 4 <= end) {
            const int4 d4 = *(const int4*)(dst + i);
            const int4 s4 = *(const int4*)(src + i);
            const float4 e4 = *(const float4*)(e + i);
            int p0 = atomicAdd(&lh[d4.x], 1);
            int p1 = atomicAdd(&lh[d4.y], 1);
            int p2 = atomicAdd(&lh[d4.z], 1);
            int p3 = atomicAdd(&lh[d4.w], 1);
            eidx[p0] = make_int2(s4.x, __float_as_int(e4.x));
            eidx[p1] = make_int2(s4.y, __float_as_int(e4.y));
            eidx[p2] = make_int2(s4.z, __float_as_int(e4.z));
            eidx[p3] = make_int2(s4.w, __float_as_int(e4.w));
        } else {
            for (int k = i; k < end; ++k) {
                const int pos = atomicAdd(&lh[dst[k]], 1);
                eidx[pos] = make_int2(src[k], __float_as_int(e[k]));
            }
        }
    }
}

// ---------------------------------------------------------------------------
// K-D: per-node gather-reduce. One WAVE per node, 4 nodes per 256-thread
// block. Half-wave pairs split even/odd edges; each 32-lane half loads a
// full h row as float4; unroll-4 keeps 4 gathers in flight per lane.
// Edge lists staged once in LDS. Final reduce: shfl_xor(32). Writes MEANS.
// ---------------------------------------------------------------------------
__global__ __launch_bounds__(256) void aggregate(
        const float* __restrict__ h, const int2* __restrict__ eidx,
        const int* __restrict__ cnt,
        float* __restrict__ mean_p, float* __restrict__ mean_u, int n_nodes) {
    __shared__ int2 se[4][CAP];   // 8 KB
    __shared__ int scnt[4];
    const int tid = threadIdx.x;
    const int w    = tid >> 6;    // wave id = local node
    const int lane = tid & 63;
    const int half = lane >> 5;   // 0: even edges, 1: odd edges
    const int hl   = lane & 31;
    const int node0 = blockIdx.x * 4;

    if (tid < 4) scnt[tid] = (node0 + tid < n_nodes) ? cnt[node0 + tid] : 0;
    __syncthreads();
    for (int i = tid; i < 4 * CAP; i += 256) {
        const int ln = i >> 8;          // CAP = 256
        const int k  = i & (CAP - 1);
        if (k < scnt[ln]) se[ln][k] = eidx[(size_t)(node0 + ln) * CAP + k];
    }
    __syncthreads();

    const int n = scnt[w];
    float4 su = make_float4(0.f, 0.f, 0.f, 0.f);
    float4 sp = make_float4(0.f, 0.f, 0.f, 0.f);
    const float* hp = h + hl * 4;

    int j = half;
    for (; j + 6 < n; j += 8) {
        const int2 e0 = se[w][j], e1 = se[w][j + 2];
        const int2 e2 = se[w][j + 4], e3 = se[w][j + 6];
        const float4 h0 = *(const float4*)(hp + (size_t)e0.x * NFEAT);
        const float4 h1 = *(const float4*)(hp + (size_t)e1.x * NFEAT);
        const float4 h2 = *(const float4*)(hp + (size_t)e2.x * NFEAT);
        const float4 h3 = *(const float4*)(hp + (size_t)e3.x * NFEAT);
        const float v0 = __int_as_float(e0.y), v1 = __int_as_float(e1.y);
        const float v2 = __int_as_float(e2.y), v3 = __int_as_float(e3.y);
        su.x += h0.x + h1.x + h2.x + h3.x;
        su.y += h0.y + h1.y + h2.y + h3.y;
        su.z += h0.z + h1.z + h2.z + h3.z;
        su.w += h0.w + h1.w + h2.w + h3.w;
        sp.x += v0 * h0.x + v1 * h1.x + v2 * h2.x + v3 * h3.x;
        sp.y += v0 * h0.y + v1 * h1.y + v2 * h2.y + v3 * h3.y;
        sp.z += v0 * h0.z + v1 * h1.z + v2 * h2.z + v3 * h3.z;
        sp.w += v0 * h0.w + v1 * h1.w + v2 * h2.w + v3 * h3.w;
    }
    for (; j < n; j += 2) {
        const int2 e0 = se[w][j];
        const float4 h0 = *(const float4*)(hp + (size_t)e0.x * NFEAT);
        const float v0 = __int_as_float(e0.y);
        su.x += h0.x; su.y += h0.y; su.z += h0.z; su.w += h0.w;
        sp.x += v0 * h0.x; sp.y += v0 * h0.y;
        sp.z += v0 * h0.z; sp.w += v0 * h0.w;
    }

    // combine even/odd halves: lane <-> lane^32 (both end with the total)
    su.x += __shfl_xor(su.x, 32); su.y += __shfl_xor(su.y, 32);
    su.z += __shfl_xor(su.z, 32); su.w += __shfl_xor(su.w, 32);
    sp.x += __shfl_xor(sp.x, 32); sp.y += __shfl_xor(sp.y, 32);
    sp.z += __shfl_xor(sp.z, 32); sp.w += __shfl_xor(sp.w, 32);

    const int node = node0 + w;
    if (half == 0 && node < n_nodes) {
        const float inv = 1.0f / fmaxf((float)n, 1.0f);
        *(float4*)(mean_u + (size_t)node * NFEAT + hl * 4) =
            make_float4(su.x * inv, su.y * inv, su.z * inv, su.w * inv);
        *(float4*)(mean_p + (size_t)node * NFEAT + hl * 4) =
            make_float4(sp.x * inv, sp.y * inv, sp.z * inv, sp.w * inv);
    }
}

// ---------------------------------------------------------------------------
// K-E: fused GEMM: out[n][o] = btot[o] + sum_{r<384} X[n][r] * Wcat[r][o],
// X = [h | mean_p | mean_u].  mean_u aliases out (staged before any write).
// ---------------------------------------------------------------------------
__global__ __launch_bounds__(256) void fused_gemm(
        const float* __restrict__ h, const float* __restrict__ mean_p,
        const float* mean_u, const float* __restrict__ Wcat,
        const float* __restrict__ btot, float* out, int n_nodes) {
    __shared__ float Xs[3][NPB][NFEAT];
    __shared__ float Wt[32][NFEAT];
    const int tid = threadIdx.x;
    const int og = tid & 31;
    const int ng = tid >> 5;
    const int o4 = og * 4;
    const int n0 = blockIdx.x * NPB;

    {
        const float* p;
        #pragma unroll
        for (int s = 0; s < 3; ++s) {
            p = (s == 0) ? h : (s == 1) ? mean_p : mean_u;
            for (int idx = tid; idx < NPB * (NFEAT / 4); idx += 256) {
                const int n = idx >> 5;
                const int c4 = idx & 31;
                const int gn = n0 + n;
                float4 v = make_float4(0.f, 0.f, 0.f, 0.f);
                if (gn < n_nodes) v = *(const float4*)(p + (size_t)gn * NFEAT + c4 * 4);
                *(float4*)(&Xs[s][n][c4 * 4]) = v;
            }
        }
    }

    float acc0[4] = {0.f, 0.f, 0.f, 0.f};
    float acc1[4] = {0.f, 0.f, 0.f, 0.f};
    const int nA = ng * 2, nB = ng * 2 + 1;

    for (int kt = 0; kt < 3 * NFEAT; kt += 32) {
        __syncthreads();
        for (int idx = tid; idx < 32 * (NFEAT / 4); idx += 256) {
            const int r = idx >> 5;
            const int c4 = idx & 31;
            *(float4*)(&Wt[r][c4 * 4]) =
                *(const float4*)(Wcat + (size_t)(kt + r) * NFEAT + c4 * 4);
        }
        __syncthreads();
        const int s  = kt >> 7;
        const int kb = kt & 127;
        #pragma unroll
        for (int kk = 0; kk < 32; kk += 4) {
            const float4 xa = *(const float4*)(&Xs[s][nA][kb + kk]);
            const float4 xb = *(const float4*)(&Xs[s][nB][kb + kk]);
            const float4 w0 = *(const float4*)(&Wt[kk + 0][o4]);
            const float4 w1 = *(const float4*)(&Wt[kk + 1][o4]);
            const float4 w2 = *(const float4*)(&Wt[kk + 2][o4]);
            const float4 w3 = *(const float4*)(&Wt[kk + 3][o4]);
            acc0[0] += xa.x*w0.x + xa.y*w1.x + xa.z*w2.x + xa.w*w3.x;
            acc0[1] += xa.x*w0.y + xa.y*w1.y + xa.z*w2.y + xa.w*w3.y;
            acc0[2] += xa.x*w0.z + xa.y*w1.z + xa.z*w2.z + xa.w*w3.z;
            acc0[3] += xa.x*w0.w + xa.y*w1.w + xa.z*w2.w + xa.w*w3.w;
            acc1[0] += xb.x*w0.x + xb.y*w1.x + xb.z*w2.x + xb.w*w3.x;
            acc1[1] += xb.x*w0.y + xb.y*w1.y + xb.z*w2.y + xb.w*w3.y;
            acc1[2] += xb.x*w0.z + xb.y*w1.z + xb.z*w2.z + xb.w*w3.z;
            acc1[3] += xb.x*w0.w + xb.y*w1.w + xb.z*w2.w + xb.w*w3.w;
        }
    }

    const float4 bt = *(const float4*)(btot + o4);
    if (n0 + nA < n_nodes) {
        float4 v = make_float4(acc0[0] + bt.x, acc0[1] + bt.y,
                               acc0[2] + bt.z, acc0[3] + bt.w);
        *(float4*)(out + (size_t)(n0 + nA) * NFEAT + o4) = v;
    }
    if (n0 + nB < n_nodes) {
        float4 v = make_float4(acc1[0] + bt.x, acc1[1] + bt.y,
                               acc1[2] + bt.z, acc1[3] + bt.w);
        *(float4*)(out + (size_t)(n0 + nB) * NFEAT + o4) = v;
    }
}

extern "C" void kernel_launch(void* const* d_in, const int* in_sizes, int n_in,
                              void* d_out, int out_size, void* d_ws, size_t ws_size,
                              hipStream_t stream) {
    const float* h     = (const float*)d_in[0];
    const float* e     = (const float*)d_in[1];
    const int*   src   = (const int*)d_in[2];
    const int*   dst   = (const int*)d_in[3];
    const float* Ws_w  = (const float*)d_in[4];
    const float* Ws_b  = (const float*)d_in[5];
    const float* Wn_w  = (const float*)d_in[6];
    const float* Wn_b  = (const float*)d_in[7];
    const float* Wu_w  = (const float*)d_in[8];
    const float* Wu_b  = (const float*)d_in[9];
    const float* lin_w = (const float*)d_in[10];
    const float* lin_b = (const float*)d_in[11];
    float* out = (float*)d_out;

    const int n_nodes = in_sizes[0] / NFEAT;
    const int n_edges = in_sizes[2];

    // ---- workspace layout ----
    char* ws = (char*)d_ws;
    float* mean_p = (float*)ws;                 ws += (size_t)n_nodes * NFEAT * 4;
    float* Wcat   = (float*)ws;                 ws += 3 * NFEAT * NFEAT * 4;
    float* btot   = (float*)ws;                 ws += NFEAT * 4;
    int2*  eidx   = (int2*)ws;                  ws += (size_t)n_nodes * CAP * 8;
    int*   cnt    = (int*)ws;                   ws += n_nodes * 4;
    // hist + base (P*n_nodes ints each, 2*P <= NFEAT so they fit exactly)
    // overlay mean_p: both are dead before aggregate first writes mean_p.
    int*   hist   = (int*)mean_p;
    int*   base   = hist + (size_t)P * n_nodes;
    float* mean_u = out;  // reuse d_out as scratch (see fused_gemm note)

    hist_weights<<<P + NFEAT, 256, 0, stream>>>(dst, hist, n_edges, n_nodes,
                                                Ws_w, Wn_w, Wu_w, Ws_b, Wn_b, Wu_b,
                                                lin_w, lin_b, Wcat, btot);

    col_scan<<<(n_nodes + 255) / 256, 256, 0, stream>>>(hist, base, cnt, n_nodes);

    scatter_csr<<<P, 256, 0, stream>>>(src, dst, e, base, eidx, n_edges, n_nodes);

    const int agg_blocks = (n_nodes + 3) / 4;
    aggregate<<<agg_blocks, 256, 0, stream>>>(h, eidx, cnt, mean_p, mean_u, n_nodes);

    const int n_blocks = (n_nodes + NPB - 1) / NPB;
    fused_gemm<<<n_blocks, 256, 0, stream>>>(h, mean_p, mean_u, Wcat, btot,
                                             out, n_nodes);
}